// Round 14
// baseline (360.595 us; speedup 1.0000x reference)
//
#include <hip/hip_runtime.h>
#include <hip/hip_bf16.h>
#include <math.h>

#define BB 8
#define LL 64
#define DD 256
#define VV 4096
#define RR 512           // BB*LL
#define K3 768

typedef __attribute__((ext_vector_type(4))) float f32x4;
typedef __attribute__((ext_vector_type(8))) short bf16x8;
typedef __attribute__((ext_vector_type(4))) unsigned short u16x4;
typedef unsigned long long u64;

// ---- workspace layout (float offsets) -----------------------------------
#define WS_ZE      0
#define WS_ZEU3    (WS_ZE + RR*DD)           // z; then M5 parts 3,4
#define WS_WCT     (WS_ZEU3 + RR*DD)         // M5 parts 0,1,2
#define WS_XSA0    (WS_WCT + DD*K3)          // scan ping (twT/cwT pre-scan)
#define WS_XSA1    (WS_XSA0 + RR*DD)         // scan pong (z2 at scan start)
#define WS_EMIT    (WS_XSA1 + RR*DD)
#define WS_YVEC    (WS_EMIT + RR*DD)
#define WS_X0VEC   (WS_YVEC + DD)
#define WS_YK      (WS_X0VEC + DD)
#define WS_YLOG    (WS_YK + DD)
#define WS_YLSE    (WS_YLOG + VV)
#define WS_SEL     (WS_YLSE + 8)
// Per-BLOCK sync tokens: 512 slots x 8 ints (32B) = 4096 ints. Plain
// relaxed stores (NO fetch_add -> no L3 RMW convoy); waiters gather-poll
// 24 neighbor slots with one per-lane load. Slot for block (rg,cg):
// (rg*8+cg)*8. Fits [WS_SEL, WS_EHI): 856840+4096 = 860936 < 861184.
#define WS_TOKS    WS_SEL
#define WS_HPART   WS_WCT                    // head partials (head runs post-scan)
// temp (pre-scan only), inside XSA0:
#define WS_TWT     WS_XSA0                   // tw^T
#define WS_CWT     (WS_XSA0 + 65536)         // cw^T
// MFMA tail:
#define WS_EHI     861184
#define WS_ELO     (WS_EHI + VV*DD/2)

__device__ __forceinline__ float waveSum(float v) {
#pragma unroll
  for (int o = 32; o > 0; o >>= 1) v += __shfl_xor(v, o, 64);
  return v;
}

__device__ __forceinline__ unsigned short f2bf(float f) {
  unsigned int u = __float_as_uint(f);
  unsigned int r = (u + 0x7fffu + ((u >> 16) & 1u)) >> 16;
  return (unsigned short)r;
}
__device__ __forceinline__ float bf2f(unsigned short h) {
  return __uint_as_float(((unsigned int)h) << 16);
}

union U64F2 { u64 u; float f[2]; };

// --- prep0: yvec + x0vec (so prep1's ylog role has yvec ready) -----------
__global__ __launch_bounds__(256) void k_prep0(
    const float* __restrict__ embed, const float* __restrict__ initw,
    float* __restrict__ ws) {
  int r = blockIdx.x, d = threadIdx.x;
  __shared__ float red[4];
  float a = (r == 0) ? embed[d] : initw[d * 16];
  float* dst = ws + ((r == 0) ? WS_YVEC : WS_X0VEC);
  int lane = d & 63, w = d >> 6;
  float s = waveSum(a);
  __syncthreads();
  if (lane == 0) red[w] = s;
  __syncthreads();
  float sum = red[0] + red[1] + red[2] + red[3];
  float sq = waveSum(a * a);
  __syncthreads();
  if (lane == 0) red[w] = sq;
  __syncthreads();
  float sqs = red[0] + red[1] + red[2] + red[3];
  float mean = sum * (1.0f / DD);
  float var = fmaxf((sqs - (float)DD * mean * mean) * (1.0f / (DD - 1)), 0.0f);
  dst[d] = a / (1e-5f + sqrtf(var));
}

// --- prep1: norm (0..513) | transposes (514..769) | split_e (770..1793)
//            | ylog (1794..1857) ------------------------------------------
__global__ __launch_bounds__(256) void k_prep1(
    const int* __restrict__ z, const float* __restrict__ embed,
    const float* __restrict__ initw, const float* __restrict__ tw,
    const float* __restrict__ cw, float* __restrict__ ws) {
  int bid = blockIdx.x, d = threadIdx.x;
  __shared__ float red[4];
  __shared__ float y[DD];
  if (bid < RR + 2) {
    float a; float* dst;
    if (bid < RR) { int tok = z[bid]; a = embed[tok * DD + d]; dst = ws + WS_ZE + bid * DD; }
    else if (bid == RR) { a = embed[d]; dst = ws + WS_YVEC; }
    else { a = initw[d * 16]; dst = ws + WS_X0VEC; }
    int lane = d & 63, w = d >> 6;
    float s = waveSum(a);
    __syncthreads();
    if (lane == 0) red[w] = s;
    __syncthreads();
    float sum = red[0] + red[1] + red[2] + red[3];
    float sq = waveSum(a * a);
    __syncthreads();
    if (lane == 0) red[w] = sq;
    __syncthreads();
    float sqs = red[0] + red[1] + red[2] + red[3];
    float mean = sum * (1.0f / DD);
    float var = fmaxf((sqs - (float)DD * mean * mean) * (1.0f / (DD - 1)), 0.0f);
    dst[d] = a / (1e-5f + sqrtf(var));
  } else if (bid < RR + 2 + 256) {
    int c = bid - (RR + 2);
    ws[WS_TWT + c * DD + d] = tw[d * DD + c];
    ws[WS_CWT + c * DD + d] = cw[d * DD + c];
  } else if (bid < RR + 2 + 256 + 1024) {
    int eb = bid - (RR + 2 + 256);
    unsigned short* eh = (unsigned short*)(ws + WS_EHI);
    unsigned short* el = (unsigned short*)(ws + WS_ELO);
    int i = (eb * 256 + d) * 4;
    float4 v = *(const float4*)(embed + i);
    float f[4] = {v.x, v.y, v.z, v.w};
    u16x4 h, l;
#pragma unroll
    for (int j = 0; j < 4; ++j) {
      unsigned short hb = f2bf(f[j]);
      h[j] = hb;
      l[j] = f2bf(f[j] - bf2f(hb));
    }
    *(u16x4*)(eh + i) = h;
    *(u16x4*)(el + i) = l;
  } else {
    int yb = bid - (RR + 2 + 256 + 1024);
    y[d] = ws[WS_YVEC + d];   // yvec from k_prep0 (prior dispatch)
    __syncthreads();
    int w = d >> 6, lane = d & 63;
    for (int i = 0; i < 16; i++) {
      int v = yb * 64 + i * 4 + w;
      float p = 0.f;
#pragma unroll
      for (int j = 0; j < 4; j++)
        p += y[lane + 64*j] * embed[(size_t)v * DD + lane + 64*j];
      p = waveSum(p);
      if (lane == 0) ws[WS_YLOG + v] = p;
    }
  }
}

// --- out[r][d] = scale*(in[r]·W[d,:] + bias[d]) ; 2 rows / block ----------
__global__ __launch_bounds__(256) void k_rowmat2(
    const float* __restrict__ in, const float* __restrict__ W,
    const float* __restrict__ bias, float* __restrict__ out, float scale) {
  int r0 = blockIdx.x * 2, d = threadIdx.x;
  __shared__ float u[2][260];
  u[0][d] = in[r0 * DD + d];
  u[1][d] = in[(r0 + 1) * DD + d];
  __syncthreads();
  float a0 = 0.f, a1 = 0.f;
  const float4* w4 = (const float4*)(W + d * DD);
  const float4* u0 = (const float4*)&u[0][0];
  const float4* u1 = (const float4*)&u[1][0];
#pragma unroll 8
  for (int k4 = 0; k4 < 64; k4++) {
    float4 w = w4[k4], x0 = u0[k4], x1 = u1[k4];
    a0 += x0.x*w.x + x0.y*w.y + x0.z*w.z + x0.w*w.w;
    a1 += x1.x*w.x + x1.y*w.y + x1.z*w.z + x1.w*w.w;
  }
  float b = bias[d];
  out[r0 * DD + d]       = (a0 + b) * scale;
  out[(r0 + 1) * DD + d] = (a1 + b) * scale;
}

// --- prep3: zmat2 (0..255) + build_w2 (256..511) + zero_tok (512..527) ---
__global__ __launch_bounds__(256) void k_prep3(
    const float* __restrict__ tw, const float* __restrict__ cw,
    float* __restrict__ ws) {
  int bid = blockIdx.x, c = threadIdx.x;
  __shared__ float zs[4][260];
  __shared__ float rA[DD], rB[DD], rC[DD];
  if (bid < 256) {
    // z2[l] = (z[l-1]@A + z[l+1]@B + z[l]@C) + z[l]
    int r0 = bid * 2;
    int b = r0 >> 6, l = r0 & 63;
    const float* zb = ws + WS_ZEU3 + (size_t)b * 64 * DD;
    float* zout = ws + WS_XSA1;
#pragma unroll
    for (int j = 0; j < 4; ++j) {
      int ll = (l + j - 1 + 64) & 63;
      zs[j][c] = zb[ll * DD + c];
    }
    __syncthreads();
    const float4* wA = (const float4*)(ws + WS_TWT + (size_t)c * DD);
    const float4* wB = (const float4*)(tw + (size_t)c * DD);
    const float4* wC = (const float4*)(ws + WS_CWT + (size_t)c * DD);
    const float4* zm0 = (const float4*)&zs[0][0];
    const float4* z00 = (const float4*)&zs[1][0];
    const float4* zp0 = (const float4*)&zs[2][0];
    const float4* zp1 = (const float4*)&zs[3][0];
    float a0 = 0.f, a1 = 0.f;
#pragma unroll 8
    for (int k4 = 0; k4 < 64; ++k4) {
      float4 A4 = wA[k4], B4 = wB[k4], C4 = wC[k4];
      float4 m0 = zm0[k4], z0 = z00[k4], p0 = zp0[k4], p1 = zp1[k4];
      a0 += m0.x*A4.x + m0.y*A4.y + m0.z*A4.z + m0.w*A4.w
          + p0.x*B4.x + p0.y*B4.y + p0.z*B4.z + p0.w*B4.w
          + z0.x*C4.x + z0.y*C4.y + z0.z*C4.z + z0.w*C4.w;
      a1 += z0.x*A4.x + z0.y*A4.y + z0.z*A4.z + z0.w*A4.w
          + p1.x*B4.x + p1.y*B4.y + p1.z*B4.z + p1.w*B4.w
          + p0.x*C4.x + p0.y*C4.y + p0.z*C4.z + p0.w*C4.w;
    }
    const float inv3 = 1.0f / 3.0f;
    zout[(size_t)r0 * DD + c]       = a0 * inv3 + zs[1][c];
    zout[(size_t)(r0 + 1) * DD + c] = a1 * inv3 + zs[2][c];
  } else if (bid < 512) {
    int k = bid - 256;
    const float* twT = ws + WS_TWT;
    const float inv9 = 1.0f / 9.0f;
    rA[c] = tw[k * DD + c] * inv9;
    rB[c] = twT[k * DD + c] * inv9;
    rC[c] = cw[k * DD + c] * inv9;
    __syncthreads();
    float a2 = 0.f, m1 = 0.f, m0 = 0.f, m3 = 0.f, b2 = 0.f;
#pragma unroll 4
    for (int j = 0; j < DD; ++j) {
      float Aj = tw[j * DD + c];
      float Bj = twT[j * DD + c];
      float Cj = cw[j * DD + c];
      float ra = rA[j], rb = rB[j], rc = rC[j];
      a2 += ra * Aj;
      m1 += rc * Aj + ra * Cj;
      m0 += rb * Aj + ra * Bj + rc * Cj;
      m3 += rc * Bj + rb * Cj;
      b2 += rb * Bj;
    }
    float* p0 = ws + WS_WCT;
    float* p3 = ws + WS_ZEU3;
    p0[k * DD + c]               = a2;
    p0[65536 + k * DD + c]       = m1;
    p0[2 * 65536 + k * DD + c]   = m0;
    p3[k * DD + c]               = m3;
    p3[65536 + k * DD + c]       = b2;
  } else {
    ((int*)(ws + WS_TOKS))[(bid - 512) * 256 + c] = 0;
  }
}

// --- persistent scan: 32 squared steps + emit tail, regular launch -------
// 512 blocks (2/CU), 256 thr; block = 8 rows x 32 cols; 5-part W (K=1280)
// in 40 f32x4. R14 sync: per-BLOCK token slot (plain store, no RMW) +
// single gather-poll load covering all 24 neighbor blocks.
__global__ __launch_bounds__(256, 2) void k_scan(
    float* __restrict__ ws, const float* __restrict__ emiw,
    const float* __restrict__ emib) {
  const int bid = blockIdx.x;
  const int rg = bid & 63, cg = bid >> 6;
  const int b = rg >> 3, rgl = rg & 7, l0 = rgl * 8;
  const int t = threadIdx.x, lane = t & 63;
  const int cl = t & 7, rs = t >> 3;
  const int c0 = cg * 32 + cl * 4;

  __shared__ float S[12 * 264];
  __shared__ float PAR[32 * 260];
  __shared__ float PAR2[4 * 256];
  __shared__ float ZB[256];

  int* tok = (int*)(ws + WS_TOKS);
  const int nb0 = b * 8 + ((rgl + 7) & 7);   // prev rowgroup (global 0..63)
  const int nb1 = b * 8 + rgl;               // own
  const int nb2 = b * 8 + ((rgl + 1) & 7);   // next
  // gather-poll address: lane -> one of 24 neighbor block slots
  int pl = lane; if (pl >= 24) pl -= 24; if (pl >= 24) pl -= 24;
  const int prg = (pl < 8) ? nb0 : (pl < 16) ? nb1 : nb2;
  const int* pollAddr = tok + (prg * 8 + (pl & 7)) * 8;
  int* myTok = tok + (nb1 * 8 + cg) * 8;

  const float* Wp[5] = {ws + WS_WCT, ws + WS_WCT + 65536, ws + WS_WCT + 2*65536,
                        ws + WS_ZEU3, ws + WS_ZEU3 + 65536};
  f32x4 wreg[40];
#pragma unroll
  for (int p = 0; p < 5; ++p)
#pragma unroll
    for (int q = 0; q < 2; ++q)
#pragma unroll
      for (int kk = 0; kk < 4; ++kk)
        wreg[p * 8 + q * 4 + kk] =
            *(const f32x4*)&Wp[p][(size_t)(rs * 8 + q * 4 + kk) * DD + c0];

  { // z2 tile from XSA1 (pre-scan by prep3-zmat2)
    int r = t >> 5, c = t & 31;
    ZB[r * 32 + c] = ws[WS_XSA1 + (size_t)(b * 64 + l0 + r) * DD + cg * 32 + c];
  }

  for (int st = 0; st < 32; ++st) {
    const float* xin  = ws + ((st & 1) ? WS_XSA1 : WS_XSA0);
    float*       xout = ws + ((st & 1) ? WS_XSA0 : WS_XSA1);

    if (st > 0) {  // every wave: one gather load polls all 24 neighbors
      while (true) {
        int v = __hip_atomic_load(pollAddr, __ATOMIC_RELAXED,
                                  __HIP_MEMORY_SCOPE_AGENT);
        if (__all(v >= st)) break;
        __builtin_amdgcn_s_sleep(1);
      }
    }

    // stage 12 rows x 256 f (1536 u64, 6/thread); st=0 -> x0vec broadcast
#pragma unroll
    for (int it = 0; it < 6; ++it) {
      int idx = it * 256 + t;
      int j = idx >> 7;
      int kk = (idx & 127) << 1;
      const u64* src = (st == 0)
          ? (const u64*)(ws + WS_X0VEC + kk)
          : (const u64*)(xin + (size_t)(b * 64 + ((l0 + j - 2 + 64) & 63)) * DD + kk);
      u64 v = __hip_atomic_load(src, __ATOMIC_RELAXED, __HIP_MEMORY_SCOPE_AGENT);
      *(u64*)(&S[j * 264 + kk]) = v;
    }
    __syncthreads();

    f32x4 acc[8];
#pragma unroll
    for (int r = 0; r < 8; ++r) acc[r] = (f32x4){0.f, 0.f, 0.f, 0.f};

#pragma unroll
    for (int p = 0; p < 5; ++p) {
#pragma unroll
      for (int r = 0; r < 8; ++r) {
        int j = r + p;
#pragma unroll
        for (int q = 0; q < 2; ++q) {
          f32x4 xv = *(const f32x4*)&S[j * 264 + rs * 8 + q * 4];
          acc[r] += xv.x * wreg[p * 8 + q * 4 + 0];
          acc[r] += xv.y * wreg[p * 8 + q * 4 + 1];
          acc[r] += xv.z * wreg[p * 8 + q * 4 + 2];
          acc[r] += xv.w * wreg[p * 8 + q * 4 + 3];
        }
      }
    }

#pragma unroll
    for (int r = 0; r < 8; ++r)
      *(f32x4*)&PAR[rs * 260 + r * 32 + cl * 4] = acc[r];
    __syncthreads();

    {
      int u = t & 63, v = t >> 6;
      f32x4 s4 = (f32x4){0.f, 0.f, 0.f, 0.f};
#pragma unroll
      for (int i = 0; i < 8; ++i)
        s4 += *(const f32x4*)&PAR[(v * 8 + i) * 260 + u * 4];
      *(f32x4*)&PAR2[v * 256 + u * 4] = s4;
    }
    __syncthreads();

    if (t < 64) {
      int r = t >> 3, c8 = t & 7;
      f32x4 s4 = (f32x4){0.f, 0.f, 0.f, 0.f};
#pragma unroll
      for (int v = 0; v < 4; ++v)
        s4 += *(const f32x4*)&PAR2[v * 256 + t * 4];
      f32x4 zb = *(const f32x4*)&ZB[r * 32 + c8 * 4];
      s4 += zb;
      size_t off = (size_t)(b * 64 + l0 + r) * DD + cg * 32 + c8 * 4;
      U64F2 lo, hi;
      lo.f[0] = s4.x; lo.f[1] = s4.y;
      hi.f[0] = s4.z; hi.f[1] = s4.w;
      __hip_atomic_store((u64*)(xout + off),     lo.u, __ATOMIC_RELAXED, __HIP_MEMORY_SCOPE_AGENT);
      __hip_atomic_store((u64*)(xout + off + 2), hi.u, __ATOMIC_RELAXED, __HIP_MEMORY_SCOPE_AGENT);
    }

    // barrier drains vmcnt(0) in every wave: this block's bypass stores are
    // at the coherence point before the token store below.
    __syncthreads();
    if (t == 0)
      __hip_atomic_store(myTok, st + 1, __ATOMIC_RELAXED,
                         __HIP_MEMORY_SCOPE_AGENT);
  }

  // ---- emit tail: wait own rowgroup's 8 blocks done, then emit tile ------
  {
    const int* ta = tok + (nb1 * 8 + (lane & 7)) * 8;
    while (true) {
      int v = __hip_atomic_load(ta, __ATOMIC_RELAXED, __HIP_MEMORY_SCOPE_AGENT);
      if (__all(v >= 32)) break;
      __builtin_amdgcn_s_sleep(1);
    }
  }
#pragma unroll
  for (int it = 0; it < 4; ++it) {
    int idx = it * 256 + t;
    int j = idx >> 7;
    int kk = (idx & 127) << 1;
    u64 v = __hip_atomic_load(
        (const u64*)(ws + WS_XSA0 + (size_t)(b * 64 + l0 + j) * DD + kk),
        __ATOMIC_RELAXED, __HIP_MEMORY_SCOPE_AGENT);
    *(u64*)(&S[j * 264 + kk]) = v;
  }
  __syncthreads();
  {
    int r = t >> 5, c = cg * 32 + (t & 31);
    const float4* wv = (const float4*)(emiw + (size_t)c * DD);
    const float4* xv = (const float4*)&S[r * 264];
    float a = 0.f;
#pragma unroll 8
    for (int k4 = 0; k4 < 64; ++k4) {
      float4 w = wv[k4], x = xv[k4];
      a += x.x*w.x + x.y*w.y + x.z*w.z + x.w*w.w;
    }
    ws[WS_EMIT + (size_t)(b * 64 + l0 + r) * DD + c] = a + emib[c];
  }
}

// --- head GEMM via MFMA, split-precision bf16, in-LDS U split ------------
__global__ __launch_bounds__(256) void k_head_mfma(
    const float* __restrict__ uemit, const float* __restrict__ uze,
    const unsigned short* __restrict__ eh, const unsigned short* __restrict__ el,
    float* __restrict__ hpart) {
  int row0 = blockIdx.x * 32;
  int v0 = blockIdx.y * 128;
  int t = threadIdx.x, lane = t & 63, w = t >> 6;
  int wr = w >> 1, wc = w & 1;
  __shared__ unsigned short UH[32 * 264];
  __shared__ unsigned short UL[32 * 264];
  const float* src = (row0 < RR) ? (uemit + (size_t)row0 * DD)
                                 : (uze + (size_t)(row0 - RR) * DD);
#pragma unroll
  for (int it = 0; it < 4; ++it) {
    int r = it * 8 + (t >> 5);
    int c8 = (t & 31) * 8;
    float4 a = *(const float4*)(src + (size_t)r * DD + c8);
    float4 b2 = *(const float4*)(src + (size_t)r * DD + c8 + 4);
    float fa[8] = {a.x, a.y, a.z, a.w, b2.x, b2.y, b2.z, b2.w};
    u16x4 h0, l0v, h1, l1;
#pragma unroll
    for (int j = 0; j < 4; ++j) {
      unsigned short hb = f2bf(fa[j]);
      h0[j] = hb; l0v[j] = f2bf(fa[j] - bf2f(hb));
      unsigned short hb1 = f2bf(fa[4 + j]);
      h1[j] = hb1; l1[j] = f2bf(fa[4 + j] - bf2f(hb1));
    }
    *(u16x4*)(&UH[r * 264 + c8])     = h0;
    *(u16x4*)(&UH[r * 264 + c8 + 4]) = h1;
    *(u16x4*)(&UL[r * 264 + c8])     = l0v;
    *(u16x4*)(&UL[r * 264 + c8 + 4]) = l1;
  }
  __syncthreads();

  f32x4 acc[4];
#pragma unroll
  for (int q = 0; q < 4; ++q) acc[q] = (f32x4){0.f, 0.f, 0.f, 0.f};

  int arow = wr * 16 + (lane & 15);
  int kof = 8 * (lane >> 4);
  const unsigned short* Ah = &UH[arow * 264 + kof];
  const unsigned short* Al = &UL[arow * 264 + kof];
  int vbase = v0 + wc * 64 + (lane & 15);

#pragma unroll
  for (int p = 0; p < 3; ++p) {
    const unsigned short* Ab = (p == 2) ? Al : Ah;
    const unsigned short* Ebl = ((p == 1) ? el : eh) + (size_t)vbase * DD + kof;
#pragma unroll
    for (int ks = 0; ks < 8; ++ks) {
      int k0 = ks * 32;
      bf16x8 a = *(const bf16x8*)(Ab + k0);
#pragma unroll
      for (int vt = 0; vt < 4; ++vt) {
        bf16x8 bfr = *(const bf16x8*)(Ebl + vt * 16 * DD + k0);
        acc[vt] = __builtin_amdgcn_mfma_f32_16x16x32_bf16(a, bfr, acc[vt], 0, 0, 0);
      }
    }
  }

  int chunk = blockIdx.y * 2 + wc;
#pragma unroll
  for (int i = 0; i < 4; ++i) {
    float mm = -1e30f;
#pragma unroll
    for (int vt = 0; vt < 4; ++vt) mm = fmaxf(mm, acc[vt][i]);
#pragma unroll
    for (int o = 1; o < 16; o <<= 1) mm = fmaxf(mm, __shfl_xor(mm, o, 64));
    float ss = 0.f;
#pragma unroll
    for (int vt = 0; vt < 4; ++vt) ss += __expf(acc[vt][i] - mm);
#pragma unroll
    for (int o = 1; o < 16; o <<= 1) ss += __shfl_xor(ss, o, 64);
    if ((lane & 15) == 0) {
      int row = row0 + wr * 16 + (lane >> 4) * 4 + i;
      hpart[((size_t)row * 64 + chunk) * 2]     = mm;
      hpart[((size_t)row * 64 + chunk) * 2 + 1] = ss;
    }
  }
}

// --- finish: yk + ylse + sel + tgt + comb + final, fused; grid(8) --------
__global__ __launch_bounds__(256) void k_finish(
    const int* __restrict__ x, const float* __restrict__ embed,
    const float* __restrict__ xks, const float* __restrict__ xkdw,
    const float* __restrict__ xkdb, float* __restrict__ ws,
    const float* __restrict__ hp, float* __restrict__ out) {
  int b = blockIdx.x, t = threadIdx.x, lane = t & 63, w = t >> 6;
  __shared__ float YK[DD];
  __shared__ float rm[4], rv[4];
  __shared__ float ylse_s;
  __shared__ float sel0[64], sel1[64], sel2[64], tg0[64], tg1[64];
  __shared__ float ls0s[64], ls1s[64];

  {
    float acc = xkdb[t];
    const float4* yv4 = (const float4*)(ws + WS_YVEC);
    const float4* w4 = (const float4*)(xkdw + (size_t)t * DD);
    float a = 0.f;
#pragma unroll 8
    for (int k4 = 0; k4 < 64; ++k4) {
      float4 yv = yv4[k4], wv = w4[k4];
      a += yv.x*wv.x + yv.y*wv.y + yv.z*wv.z + yv.w*wv.w;
    }
    YK[t] = acc + a;
  }
  {
    float m = -1e30f, s = 0.f;
    for (int v = t; v < VV; v += 256) {
      float lg = ws[WS_YLOG + v];
      float mn = fmaxf(m, lg);
      s = s * __expf(m - mn) + __expf(lg - mn);
      m = mn;
    }
#pragma unroll
    for (int o = 32; o > 0; o >>= 1) {
      float mo = __shfl_xor(m, o, 64), so = __shfl_xor(s, o, 64);
      float mn = fmaxf(m, mo);
      s = s * __expf(m - mn) + so * __expf(mo - mn);
      m = mn;
    }
    if (lane == 0) { rm[w] = m; rv[w] = s; }
  }
  __syncthreads();
  if (t == 0) {
    float M = fmaxf(fmaxf(rm[0], rm[1]), fmaxf(rm[2], rm[3]));
    float S = rv[0]*__expf(rm[0]-M) + rv[1]*__expf(rm[1]-M) +
              rv[2]*__expf(rm[2]-M) + rv[3]*__expf(rm[3]-M);
    ylse_s = M + logf(S);
  }

  for (int i = 0; i < 16; ++i) {
    int l = w * 16 + i, r = b * 64 + l;
    float4 xs = *(const float4*)&ws[WS_XSA0 + (size_t)r * DD + lane * 4];
    float4 k0 = *(const float4*)&xks[lane * 4];
    float4 k1 = *(const float4*)&xks[DD + lane * 4];
    float4 yk4 = *(const float4*)&YK[lane * 4];
    float s0 = waveSum(xs.x*k0.x + xs.y*k0.y + xs.z*k0.z + xs.w*k0.w);
    float s1 = waveSum(xs.x*k1.x + xs.y*k1.y + xs.z*k1.z + xs.w*k1.w);
    float s2 = waveSum(xs.x*yk4.x + xs.y*yk4.y + xs.z*yk4.z + xs.w*yk4.w);
    int xv = x[r];
    float4 e4 = *(const float4*)&embed[(size_t)xv * DD + lane * 4];
    float4 em = *(const float4*)&ws[WS_EMIT + (size_t)r * DD + lane * 4];
    float4 zr = *(const float4*)&ws[WS_ZE + (size_t)r * DD + lane * 4];
    float t0 = waveSum(em.x*e4.x + em.y*e4.y + em.z*e4.z + em.w*e4.w);
    float t1 = waveSum(zr.x*e4.x + zr.y*e4.y + zr.z*e4.z + zr.w*e4.w);
    float m0 = hp[((size_t)r * 64 + lane) * 2];
    float q0 = hp[((size_t)r * 64 + lane) * 2 + 1];
    float m1 = hp[((size_t)(RR + r) * 64 + lane) * 2];
    float q1 = hp[((size_t)(RR + r) * 64 + lane) * 2 + 1];
#pragma unroll
    for (int o = 32; o > 0; o >>= 1) {
      float mo = __shfl_xor(m0, o, 64), so = __shfl_xor(q0, o, 64);
      float mn = fmaxf(m0, mo);
      q0 = q0 * __expf(m0 - mn) + so * __expf(mo - mn);
      m0 = mn;
      mo = __shfl_xor(m1, o, 64); so = __shfl_xor(q1, o, 64);
      mn = fmaxf(m1, mo);
      q1 = q1 * __expf(m1 - mn) + so * __expf(mo - mn);
      m1 = mn;
    }
    if (lane == 0) {
      sel0[l] = s0; sel1[l] = s1; sel2[l] = s2;
      tg0[l] = t0; tg1[l] = t1;
      ls0s[l] = m0 + logf(q0);
      ls1s[l] = m1 + logf(q1);
    }
  }
  __syncthreads();
  if (w == 0) {
    int l = lane, r = b * 64 + l;
    float s0 = sel0[l], s1 = sel1[l], s2 = sel2[l];
    float mx = fmaxf(s0, fmaxf(s1, s2));
    float den = expf(s0 - mx) + expf(s1 - mx) + 64.f * expf(s2 - mx);
    float lsel = mx + logf(den);
    int xv = x[r];
    float P0 = expf(s0 - lsel + tg0[l] - ls0s[l]);
    float P1 = expf(s1 - lsel + tg1[l] - ls1s[l]);
    float Py = expf(s2 - lsel + ws[WS_YLOG + xv] - ylse_s);
    float cent = sqrtf(P0 + P1 + 64.f * Py);
    float sum = waveSum(cent);
    if (lane == 0) out[b] = -(sum * (1.0f / 64.f));
  }
}

extern "C" void kernel_launch(void* const* d_in, const int* in_sizes, int n_in,
                              void* d_out, int out_size, void* d_ws, size_t ws_size,
                              hipStream_t stream) {
  (void)in_sizes; (void)n_in; (void)out_size; (void)ws_size;
  const int*   x     = (const int*)d_in[0];
  const int*   z     = (const int*)d_in[1];
  const float* embed = (const float*)d_in[2];
  const float* initw = (const float*)d_in[3];
  const float* tw    = (const float*)d_in[4];
  const float* tb    = (const float*)d_in[5];
  const float* cw    = (const float*)d_in[6];
  const float* uw    = (const float*)d_in[7];
  const float* xks   = (const float*)d_in[8];
  const float* xkdw  = (const float*)d_in[9];
  const float* xkdb  = (const float*)d_in[10];
  const float* emiw  = (const float*)d_in[11];
  const float* emib  = (const float*)d_in[12];
  float* ws  = (float*)d_ws;
  float* out = (float*)d_out;

  const unsigned short* ehg = (const unsigned short*)(ws + WS_EHI);
  const unsigned short* elg = (const unsigned short*)(ws + WS_ELO);
  float* hpart = ws + WS_HPART;

  // P0: yvec/x0vec (prep1's ylog role needs yvec)
  hipLaunchKernelGGL(k_prep0, dim3(2), dim3(256), 0, stream, embed, initw, ws);
  // P1: ze-norm + transposes + split_e + ylog
  hipLaunchKernelGGL(k_prep1, dim3(RR + 2 + 256 + 1024 + 64), dim3(256), 0,
                     stream, z, embed, initw, tw, cw, ws);
  // P2: zeu3 = (ze @ uw^T + tb)/3
  hipLaunchKernelGGL(k_rowmat2, dim3(256), dim3(256), 0, stream,
                     ws + WS_ZE, uw, tb, ws + WS_ZEU3, 1.0f / 3.0f);
  // P3: z2 + squared-operator matrices + token zero
  hipLaunchKernelGGL(k_prep3, dim3(528), dim3(256), 0, stream, tw, cw, ws);
  // SCAN (pure, 512 blocks) + emit tail
  hipLaunchKernelGGL(k_scan, dim3(512), dim3(256), 0, stream, ws, emiw, emib);
  // Head (full grid) + finish
  hipLaunchKernelGGL(k_head_mfma, dim3(32, 32), dim3(256), 0, stream,
                     ws + WS_EMIT, ws + WS_ZE, ehg, elg, hpart);
  hipLaunchKernelGGL(k_finish, dim3(8), dim3(256), 0, stream,
                     x, embed, xks, xkdw, xkdb, ws, hpart, out);
}

// Round 15
// 355.051 us; speedup vs baseline: 1.0156x; 1.0156x over previous
//
#include <hip/hip_runtime.h>
#include <hip/hip_bf16.h>
#include <math.h>

#define BB 8
#define LL 64
#define DD 256
#define VV 4096
#define RR 512           // BB*LL
#define K3 768

typedef __attribute__((ext_vector_type(4))) float f32x4;
typedef __attribute__((ext_vector_type(8))) short bf16x8;
typedef __attribute__((ext_vector_type(4))) unsigned short u16x4;
typedef unsigned long long u64;

// ---- workspace layout (float offsets) -----------------------------------
#define WS_ZE      0
#define WS_ZEU3    (WS_ZE + RR*DD)           // z; then M5 parts 3,4
#define WS_WCT     (WS_ZEU3 + RR*DD)         // M5 parts 0,1,2
#define WS_XSA0    (WS_WCT + DD*K3)          // scan ping (twT/cwT pre-scan)
#define WS_XSA1    (WS_XSA0 + RR*DD)         // scan pong (z2 at scan start)
#define WS_EMIT    (WS_XSA1 + RR*DD)
#define WS_YVEC    (WS_EMIT + RR*DD)
#define WS_X0VEC   (WS_YVEC + DD)
#define WS_YK      (WS_X0VEC + DD)
#define WS_YLOG    (WS_YK + DD)
#define WS_YLSE    (WS_YLOG + VV)
#define WS_SEL     (WS_YLSE + 8)
// Per-BLOCK sync tokens: 512 slots x 8 ints (32B). Plain relaxed stores;
// gather-poll. Token values: step 1..32, then 33 after emit.
#define WS_TOKS    WS_SEL
#define WS_HPART_SMALL WS_WCT                // fallback overlay (head post-scan)
// temp (pre-scan only), inside XSA0:
#define WS_TWT     WS_XSA0                   // tw^T
#define WS_CWT     (WS_XSA0 + 65536)         // cw^T
// MFMA tail:
#define WS_EHI     861184
#define WS_ELO     (WS_EHI + VV*DD/2)
#define WS_HPHI    (WS_ELO + VV*DD/2)        // fresh hpart (big mode)
#define WS_BIG_FLOATS (WS_HPHI + 1024*64*2)  // 8,163,328 B (R13-proven fits)

__device__ __forceinline__ float waveSum(float v) {
#pragma unroll
  for (int o = 32; o > 0; o >>= 1) v += __shfl_xor(v, o, 64);
  return v;
}

__device__ __forceinline__ unsigned short f2bf(float f) {
  unsigned int u = __float_as_uint(f);
  unsigned int r = (u + 0x7fffu + ((u >> 16) & 1u)) >> 16;
  return (unsigned short)r;
}
__device__ __forceinline__ float bf2f(unsigned short h) {
  return __uint_as_float(((unsigned int)h) << 16);
}

union U64F2 { u64 u; float f[2]; };

// --- shared head tile: 32 rows x 128 v, split-bf16 MFMA, online (m,s) ----
// bypass=true: U rows read via agent-scope u64 loads (same-kernel emit).
__device__ __forceinline__ void head_tile(
    int row0, int vy, const float* __restrict__ uemit,
    const float* __restrict__ uze,
    const unsigned short* __restrict__ eh, const unsigned short* __restrict__ el,
    float* __restrict__ hpart, float* shbuf, int t, bool bypass) {
  unsigned short* UH = (unsigned short*)shbuf;
  unsigned short* UL = UH + 32 * 264;
  int lane = t & 63, w = t >> 6;
  int wr = w >> 1, wc = w & 1;
  const float* src = (row0 < RR) ? (uemit + (size_t)row0 * DD)
                                 : (uze + (size_t)(row0 - RR) * DD);
  __syncthreads();   // prior users of shbuf done
#pragma unroll
  for (int it = 0; it < 4; ++it) {
    int r = it * 8 + (t >> 5);
    int c8 = (t & 31) * 8;
    float fa[8];
    if (bypass) {
#pragma unroll
      for (int j = 0; j < 4; ++j) {
        U64F2 v;
        v.u = __hip_atomic_load((const u64*)(src + (size_t)r * DD + c8 + j * 2),
                                __ATOMIC_RELAXED, __HIP_MEMORY_SCOPE_AGENT);
        fa[j * 2] = v.f[0]; fa[j * 2 + 1] = v.f[1];
      }
    } else {
      float4 a = *(const float4*)(src + (size_t)r * DD + c8);
      float4 b2 = *(const float4*)(src + (size_t)r * DD + c8 + 4);
      fa[0]=a.x; fa[1]=a.y; fa[2]=a.z; fa[3]=a.w;
      fa[4]=b2.x; fa[5]=b2.y; fa[6]=b2.z; fa[7]=b2.w;
    }
    u16x4 h0, l0v, h1, l1;
#pragma unroll
    for (int j = 0; j < 4; ++j) {
      unsigned short hb = f2bf(fa[j]);
      h0[j] = hb; l0v[j] = f2bf(fa[j] - bf2f(hb));
      unsigned short hb1 = f2bf(fa[4 + j]);
      h1[j] = hb1; l1[j] = f2bf(fa[4 + j] - bf2f(hb1));
    }
    *(u16x4*)(&UH[r * 264 + c8])     = h0;
    *(u16x4*)(&UH[r * 264 + c8 + 4]) = h1;
    *(u16x4*)(&UL[r * 264 + c8])     = l0v;
    *(u16x4*)(&UL[r * 264 + c8 + 4]) = l1;
  }
  __syncthreads();

  f32x4 acc[4];
#pragma unroll
  for (int q = 0; q < 4; ++q) acc[q] = (f32x4){0.f, 0.f, 0.f, 0.f};

  int arow = wr * 16 + (lane & 15);
  int kof = 8 * (lane >> 4);
  const unsigned short* Ah = &UH[arow * 264 + kof];
  const unsigned short* Al = &UL[arow * 264 + kof];
  int vbase = vy * 128 + wc * 64 + (lane & 15);

#pragma unroll
  for (int p = 0; p < 3; ++p) {
    const unsigned short* Ab = (p == 2) ? Al : Ah;
    const unsigned short* Ebl = ((p == 1) ? el : eh) + (size_t)vbase * DD + kof;
#pragma unroll
    for (int ks = 0; ks < 8; ++ks) {
      int k0 = ks * 32;
      bf16x8 a = *(const bf16x8*)(Ab + k0);
#pragma unroll
      for (int vt = 0; vt < 4; ++vt) {
        bf16x8 bfr = *(const bf16x8*)(Ebl + vt * 16 * DD + k0);
        acc[vt] = __builtin_amdgcn_mfma_f32_16x16x32_bf16(a, bfr, acc[vt], 0, 0, 0);
      }
    }
  }

  int chunk = vy * 2 + wc;
#pragma unroll
  for (int i = 0; i < 4; ++i) {
    float mm = -1e30f;
#pragma unroll
    for (int vt = 0; vt < 4; ++vt) mm = fmaxf(mm, acc[vt][i]);
#pragma unroll
    for (int o = 1; o < 16; o <<= 1) mm = fmaxf(mm, __shfl_xor(mm, o, 64));
    float ss = 0.f;
#pragma unroll
    for (int vt = 0; vt < 4; ++vt) ss += __expf(acc[vt][i] - mm);
#pragma unroll
    for (int o = 1; o < 16; o <<= 1) ss += __shfl_xor(ss, o, 64);
    if ((lane & 15) == 0) {
      int row = row0 + wr * 16 + (lane >> 4) * 4 + i;
      hpart[((size_t)row * 64 + chunk) * 2]     = mm;
      hpart[((size_t)row * 64 + chunk) * 2 + 1] = ss;
    }
  }
}

// --- prep1: ze-norm+zeu3 (0..511) | yvec/x0vec (512,513) | transposes
//            (514..769) | split_e (770..1793) | ylog (1794..1857) ---------
__global__ __launch_bounds__(256) void k_prep1(
    const int* __restrict__ z, const float* __restrict__ embed,
    const float* __restrict__ initw, const float* __restrict__ tw,
    const float* __restrict__ cw, const float* __restrict__ uw,
    const float* __restrict__ tb, float* __restrict__ ws) {
  int bid = blockIdx.x, d = threadIdx.x;
  __shared__ float red[4];
  __shared__ float u[260];
  if (bid < RR + 2) {
    float a; float* dst;
    if (bid < RR) { int tok = z[bid]; a = embed[tok * DD + d]; dst = ws + WS_ZE + bid * DD; }
    else if (bid == RR) { a = embed[d]; dst = ws + WS_YVEC; }
    else { a = initw[d * 16]; dst = ws + WS_X0VEC; }
    int lane = d & 63, w = d >> 6;
    float s = waveSum(a);
    __syncthreads();
    if (lane == 0) red[w] = s;
    __syncthreads();
    float sum = red[0] + red[1] + red[2] + red[3];
    float sq = waveSum(a * a);
    __syncthreads();
    if (lane == 0) red[w] = sq;
    __syncthreads();
    float sqs = red[0] + red[1] + red[2] + red[3];
    float mean = sum * (1.0f / DD);
    float var = fmaxf((sqs - (float)DD * mean * mean) * (1.0f / (DD - 1)), 0.0f);
    float nv = a / (1e-5f + sqrtf(var));
    dst[d] = nv;
    if (bid < RR) {
      // fused zeu3[bid][d] = (ze_row . uw[d,:] + tb[d]) / 3
      u[d] = nv;
      __syncthreads();
      float a0 = 0.f;
      const float4* w4 = (const float4*)(uw + (size_t)d * DD);
      const float4* u0 = (const float4*)&u[0];
#pragma unroll 8
      for (int k4 = 0; k4 < 64; ++k4) {
        float4 wv = w4[k4], x0 = u0[k4];
        a0 += x0.x*wv.x + x0.y*wv.y + x0.z*wv.z + x0.w*wv.w;
      }
      ws[WS_ZEU3 + (size_t)bid * DD + d] = (a0 + tb[d]) * (1.0f / 3.0f);
    }
  } else if (bid < RR + 2 + 256) {
    int c = bid - (RR + 2);
    ws[WS_TWT + c * DD + d] = tw[d * DD + c];
    ws[WS_CWT + c * DD + d] = cw[d * DD + c];
  } else if (bid < RR + 2 + 256 + 1024) {
    int eb = bid - (RR + 2 + 256);
    unsigned short* eh = (unsigned short*)(ws + WS_EHI);
    unsigned short* el = (unsigned short*)(ws + WS_ELO);
    int i = (eb * 256 + d) * 4;
    float4 v = *(const float4*)(embed + i);
    float f[4] = {v.x, v.y, v.z, v.w};
    u16x4 h, l;
#pragma unroll
    for (int j = 0; j < 4; ++j) {
      unsigned short hb = f2bf(f[j]);
      h[j] = hb;
      l[j] = f2bf(f[j] - bf2f(hb));
    }
    *(u16x4*)(eh + i) = h;
    *(u16x4*)(el + i) = l;
  } else {
    // ylog: compute yvec REDUNDANTLY in-block (no cross-block dep)
    int yb = bid - (RR + 2 + 256 + 1024);
    float a = embed[d];
    int lane = d & 63, w = d >> 6;
    float s = waveSum(a);
    __syncthreads();
    if (lane == 0) red[w] = s;
    __syncthreads();
    float sum = red[0] + red[1] + red[2] + red[3];
    float sq = waveSum(a * a);
    __syncthreads();
    if (lane == 0) red[w] = sq;
    __syncthreads();
    float sqs = red[0] + red[1] + red[2] + red[3];
    float mean = sum * (1.0f / DD);
    float var = fmaxf((sqs - (float)DD * mean * mean) * (1.0f / (DD - 1)), 0.0f);
    u[d] = a / (1e-5f + sqrtf(var));
    __syncthreads();
    for (int i = 0; i < 16; i++) {
      int v = yb * 64 + i * 4 + w;
      float p = 0.f;
#pragma unroll
      for (int j = 0; j < 4; j++)
        p += u[lane + 64*j] * embed[(size_t)v * DD + lane + 64*j];
      p = waveSum(p);
      if (lane == 0) ws[WS_YLOG + v] = p;
    }
  }
}

// --- prep3: zmat2 (0..255) + build_w2 (256..511) + zero_tok (512..527) ---
__global__ __launch_bounds__(256) void k_prep3(
    const float* __restrict__ tw, const float* __restrict__ cw,
    float* __restrict__ ws) {
  int bid = blockIdx.x, c = threadIdx.x;
  __shared__ float zs[4][260];
  __shared__ float rA[DD], rB[DD], rC[DD];
  if (bid < 256) {
    // z2[l] = (z[l-1]@A + z[l+1]@B + z[l]@C) + z[l]
    int r0 = bid * 2;
    int b = r0 >> 6, l = r0 & 63;
    const float* zb = ws + WS_ZEU3 + (size_t)b * 64 * DD;
    float* zout = ws + WS_XSA1;
#pragma unroll
    for (int j = 0; j < 4; ++j) {
      int ll = (l + j - 1 + 64) & 63;
      zs[j][c] = zb[ll * DD + c];
    }
    __syncthreads();
    const float4* wA = (const float4*)(ws + WS_TWT + (size_t)c * DD);
    const float4* wB = (const float4*)(tw + (size_t)c * DD);
    const float4* wC = (const float4*)(ws + WS_CWT + (size_t)c * DD);
    const float4* zm0 = (const float4*)&zs[0][0];
    const float4* z00 = (const float4*)&zs[1][0];
    const float4* zp0 = (const float4*)&zs[2][0];
    const float4* zp1 = (const float4*)&zs[3][0];
    float a0 = 0.f, a1 = 0.f;
#pragma unroll 8
    for (int k4 = 0; k4 < 64; ++k4) {
      float4 A4 = wA[k4], B4 = wB[k4], C4 = wC[k4];
      float4 m0 = zm0[k4], z0 = z00[k4], p0 = zp0[k4], p1 = zp1[k4];
      a0 += m0.x*A4.x + m0.y*A4.y + m0.z*A4.z + m0.w*A4.w
          + p0.x*B4.x + p0.y*B4.y + p0.z*B4.z + p0.w*B4.w
          + z0.x*C4.x + z0.y*C4.y + z0.z*C4.z + z0.w*C4.w;
      a1 += z0.x*A4.x + z0.y*A4.y + z0.z*A4.z + z0.w*A4.w
          + p1.x*B4.x + p1.y*B4.y + p1.z*B4.z + p1.w*B4.w
          + p0.x*C4.x + p0.y*C4.y + p0.z*C4.z + p0.w*C4.w;
    }
    const float inv3 = 1.0f / 3.0f;
    zout[(size_t)r0 * DD + c]       = a0 * inv3 + zs[1][c];
    zout[(size_t)(r0 + 1) * DD + c] = a1 * inv3 + zs[2][c];
  } else if (bid < 512) {
    int k = bid - 256;
    const float* twT = ws + WS_TWT;
    const float inv9 = 1.0f / 9.0f;
    rA[c] = tw[k * DD + c] * inv9;
    rB[c] = twT[k * DD + c] * inv9;
    rC[c] = cw[k * DD + c] * inv9;
    __syncthreads();
    float a2 = 0.f, m1 = 0.f, m0 = 0.f, m3 = 0.f, b2 = 0.f;
#pragma unroll 4
    for (int j = 0; j < DD; ++j) {
      float Aj = tw[j * DD + c];
      float Bj = twT[j * DD + c];
      float Cj = cw[j * DD + c];
      float ra = rA[j], rb = rB[j], rc = rC[j];
      a2 += ra * Aj;
      m1 += rc * Aj + ra * Cj;
      m0 += rb * Aj + ra * Bj + rc * Cj;
      m3 += rc * Bj + rb * Cj;
      b2 += rb * Bj;
    }
    float* p0 = ws + WS_WCT;
    float* p3 = ws + WS_ZEU3;
    p0[k * DD + c]               = a2;
    p0[65536 + k * DD + c]       = m1;
    p0[2 * 65536 + k * DD + c]   = m0;
    p3[k * DD + c]               = m3;
    p3[65536 + k * DD + c]       = b2;
  } else {
    ((int*)(ws + WS_TOKS))[(bid - 512) * 256 + c] = 0;
  }
}

// --- persistent scan: 32 squared steps + emit + (big) head tiles ---------
// 512 blocks (2/CU), 256 thr; block = 8 rows x 32 cols; W (K=1280) in 40
// f32x4. Per-block token slots (plain store); gather-poll. Head tiles run
// SEQUENTIALLY after each block's emit (R13 lesson: no concurrent extras).
__global__ __launch_bounds__(256, 2) void k_scan(
    float* __restrict__ ws, const float* __restrict__ emiw,
    const float* __restrict__ emib, const unsigned short* __restrict__ eh,
    const unsigned short* __restrict__ el, float* __restrict__ hpart,
    int doHead) {
  const int bid = blockIdx.x;
  const int rg = bid & 63, cg = bid >> 6;
  const int b = rg >> 3, rgl = rg & 7, l0 = rgl * 8;
  const int t = threadIdx.x, lane = t & 63;
  const int cl = t & 7, rs = t >> 3;
  const int c0 = cg * 32 + cl * 4;

  __shared__ float SH[12800];   // scan: S|PAR|PAR2|ZB ; head: UH|UL
  float* S    = SH;             // 12*264 = 3168
  float* PAR  = SH + 3168;      // 32*260 = 8320
  float* PAR2 = SH + 11488;     // 1024
  float* ZB   = SH + 12512;     // 256

  int* tok = (int*)(ws + WS_TOKS);
  const int nb0 = b * 8 + ((rgl + 7) & 7);
  const int nb1 = b * 8 + rgl;
  const int nb2 = b * 8 + ((rgl + 1) & 7);
  int pl = lane; if (pl >= 24) pl -= 24; if (pl >= 24) pl -= 24;
  const int prg = (pl < 8) ? nb0 : (pl < 16) ? nb1 : nb2;
  const int* pollAddr = tok + (prg * 8 + (pl & 7)) * 8;
  int* myTok = tok + (nb1 * 8 + cg) * 8;

  const float* Wp[5] = {ws + WS_WCT, ws + WS_WCT + 65536, ws + WS_WCT + 2*65536,
                        ws + WS_ZEU3, ws + WS_ZEU3 + 65536};
  f32x4 wreg[40];
#pragma unroll
  for (int p = 0; p < 5; ++p)
#pragma unroll
    for (int q = 0; q < 2; ++q)
#pragma unroll
      for (int kk = 0; kk < 4; ++kk)
        wreg[p * 8 + q * 4 + kk] =
            *(const f32x4*)&Wp[p][(size_t)(rs * 8 + q * 4 + kk) * DD + c0];

  { // z2 tile from XSA1 (pre-scan by prep3-zmat2)
    int r = t >> 5, c = t & 31;
    ZB[r * 32 + c] = ws[WS_XSA1 + (size_t)(b * 64 + l0 + r) * DD + cg * 32 + c];
  }

  for (int st = 0; st < 32; ++st) {
    const float* xin  = ws + ((st & 1) ? WS_XSA1 : WS_XSA0);
    float*       xout = ws + ((st & 1) ? WS_XSA0 : WS_XSA1);

    if (st > 0) {
      while (true) {
        int v = __hip_atomic_load(pollAddr, __ATOMIC_RELAXED,
                                  __HIP_MEMORY_SCOPE_AGENT);
        if (__all(v >= st)) break;
        __builtin_amdgcn_s_sleep(1);
      }
    }

#pragma unroll
    for (int it = 0; it < 6; ++it) {
      int idx = it * 256 + t;
      int j = idx >> 7;
      int kk = (idx & 127) << 1;
      const u64* src = (st == 0)
          ? (const u64*)(ws + WS_X0VEC + kk)
          : (const u64*)(xin + (size_t)(b * 64 + ((l0 + j - 2 + 64) & 63)) * DD + kk);
      u64 v = __hip_atomic_load(src, __ATOMIC_RELAXED, __HIP_MEMORY_SCOPE_AGENT);
      *(u64*)(&S[j * 264 + kk]) = v;
    }
    __syncthreads();

    f32x4 acc[8];
#pragma unroll
    for (int r = 0; r < 8; ++r) acc[r] = (f32x4){0.f, 0.f, 0.f, 0.f};

#pragma unroll
    for (int p = 0; p < 5; ++p) {
#pragma unroll
      for (int r = 0; r < 8; ++r) {
        int j = r + p;
#pragma unroll
        for (int q = 0; q < 2; ++q) {
          f32x4 xv = *(const f32x4*)&S[j * 264 + rs * 8 + q * 4];
          acc[r] += xv.x * wreg[p * 8 + q * 4 + 0];
          acc[r] += xv.y * wreg[p * 8 + q * 4 + 1];
          acc[r] += xv.z * wreg[p * 8 + q * 4 + 2];
          acc[r] += xv.w * wreg[p * 8 + q * 4 + 3];
        }
      }
    }

#pragma unroll
    for (int r = 0; r < 8; ++r)
      *(f32x4*)&PAR[rs * 260 + r * 32 + cl * 4] = acc[r];
    __syncthreads();

    {
      int u = t & 63, v = t >> 6;
      f32x4 s4 = (f32x4){0.f, 0.f, 0.f, 0.f};
#pragma unroll
      for (int i = 0; i < 8; ++i)
        s4 += *(const f32x4*)&PAR[(v * 8 + i) * 260 + u * 4];
      *(f32x4*)&PAR2[v * 256 + u * 4] = s4;
    }
    __syncthreads();

    if (t < 64) {
      int r = t >> 3, c8 = t & 7;
      f32x4 s4 = (f32x4){0.f, 0.f, 0.f, 0.f};
#pragma unroll
      for (int v = 0; v < 4; ++v)
        s4 += *(const f32x4*)&PAR2[v * 256 + t * 4];
      f32x4 zb = *(const f32x4*)&ZB[r * 32 + c8 * 4];
      s4 += zb;
      size_t off = (size_t)(b * 64 + l0 + r) * DD + cg * 32 + c8 * 4;
      U64F2 lo, hi;
      lo.f[0] = s4.x; lo.f[1] = s4.y;
      hi.f[0] = s4.z; hi.f[1] = s4.w;
      __hip_atomic_store((u64*)(xout + off),     lo.u, __ATOMIC_RELAXED, __HIP_MEMORY_SCOPE_AGENT);
      __hip_atomic_store((u64*)(xout + off + 2), hi.u, __ATOMIC_RELAXED, __HIP_MEMORY_SCOPE_AGENT);
    }

    __syncthreads();   // drains vmcnt(0): bypass stores visible first
    if (t == 0)
      __hip_atomic_store(myTok, st + 1, __ATOMIC_RELAXED,
                         __HIP_MEMORY_SCOPE_AGENT);
  }

  // ---- emit tail: wait own rowgroup done, compute, bypass-store ----------
  {
    const int* ta = tok + (nb1 * 8 + (lane & 7)) * 8;
    while (true) {
      int v = __hip_atomic_load(ta, __ATOMIC_RELAXED, __HIP_MEMORY_SCOPE_AGENT);
      if (__all(v >= 32)) break;
      __builtin_amdgcn_s_sleep(1);
    }
  }
#pragma unroll
  for (int it = 0; it < 4; ++it) {
    int idx = it * 256 + t;
    int j = idx >> 7;
    int kk = (idx & 127) << 1;
    u64 v = __hip_atomic_load(
        (const u64*)(ws + WS_XSA0 + (size_t)(b * 64 + l0 + j) * DD + kk),
        __ATOMIC_RELAXED, __HIP_MEMORY_SCOPE_AGENT);
    *(u64*)(&S[j * 264 + kk]) = v;
  }
  __syncthreads();
  float* EM = PAR;   // 8 x 32 staging for u64 emit stores
  {
    int r = t >> 5, c = t & 31;
    const float4* wv = (const float4*)(emiw + (size_t)(cg * 32 + c) * DD);
    const float4* xv = (const float4*)&S[r * 264];
    float a = 0.f;
#pragma unroll 8
    for (int k4 = 0; k4 < 64; ++k4) {
      float4 w = wv[k4], x = xv[k4];
      a += x.x*w.x + x.y*w.y + x.z*w.z + x.w*w.w;
    }
    EM[r * 32 + c] = a + emib[cg * 32 + c];
  }
  __syncthreads();
  if (t < 128) {
    int r = t >> 4, c2 = (t & 15) * 2;
    U64F2 v;
    v.f[0] = EM[r * 32 + c2];
    v.f[1] = EM[r * 32 + c2 + 1];
    __hip_atomic_store(
        (u64*)(ws + WS_EMIT + (size_t)(b * 64 + l0 + r) * DD + cg * 32 + c2),
        v.u, __ATOMIC_RELAXED, __HIP_MEMORY_SCOPE_AGENT);
  }
  __syncthreads();   // drain emit stores before token 33
  if (t == 0)
    __hip_atomic_store(myTok, 33, __ATOMIC_RELAXED, __HIP_MEMORY_SCOPE_AGENT);

  if (!doHead) return;

  // ---- head phase (sequential, 2 tiles per block) -------------------------
  // T1: ZE tile (rows 512+, inputs ready pre-launch) — no wait.
  {
    int T1 = bid + 512;
    head_tile((T1 >> 5) * 32, T1 & 31, ws + WS_EMIT, ws + WS_ZE,
              eh, el, hpart, SH, t, false);
  }
  // T0: EMIT tile — wait for the 4 rowgroups' 32 blocks to post 33.
  {
    int ri0 = bid >> 5, vc0 = bid & 31;
    int pl2 = lane & 31;
    const int* ta = tok + ((ri0 * 4 + (pl2 >> 3)) * 8 + (pl2 & 7)) * 8;
    while (true) {
      int v = __hip_atomic_load(ta, __ATOMIC_RELAXED, __HIP_MEMORY_SCOPE_AGENT);
      if (__all(v >= 33)) break;
      __builtin_amdgcn_s_sleep(1);
    }
    head_tile(ri0 * 32, vc0, ws + WS_EMIT, ws + WS_ZE,
              eh, el, hpart, SH, t, true);
  }
}

// --- standalone head kernel (fallback, !big) ------------------------------
__global__ __launch_bounds__(256) void k_head_mfma(
    const float* __restrict__ uemit, const float* __restrict__ uze,
    const unsigned short* __restrict__ eh, const unsigned short* __restrict__ el,
    float* __restrict__ hpart) {
  __shared__ float SH[8448];
  head_tile(blockIdx.x * 32, blockIdx.y, uemit, uze, eh, el, hpart, SH,
            threadIdx.x, false);
}

// --- finish: yk + ylse + sel + tgt + comb + final, fused; grid(8) --------
__global__ __launch_bounds__(256) void k_finish(
    const int* __restrict__ x, const float* __restrict__ embed,
    const float* __restrict__ xks, const float* __restrict__ xkdw,
    const float* __restrict__ xkdb, float* __restrict__ ws,
    const float* __restrict__ hp, float* __restrict__ out) {
  int b = blockIdx.x, t = threadIdx.x, lane = t & 63, w = t >> 6;
  __shared__ float YK[DD];
  __shared__ float rm[4], rv[4];
  __shared__ float ylse_s;
  __shared__ float sel0[64], sel1[64], sel2[64], tg0[64], tg1[64];
  __shared__ float ls0s[64], ls1s[64];

  {
    float acc = xkdb[t];
    const float4* yv4 = (const float4*)(ws + WS_YVEC);
    const float4* w4 = (const float4*)(xkdw + (size_t)t * DD);
    float a = 0.f;
#pragma unroll 8
    for (int k4 = 0; k4 < 64; ++k4) {
      float4 yv = yv4[k4], wv = w4[k4];
      a += yv.x*wv.x + yv.y*wv.y + yv.z*wv.z + yv.w*wv.w;
    }
    YK[t] = acc + a;
  }
  {
    float m = -1e30f, s = 0.f;
    for (int v = t; v < VV; v += 256) {
      float lg = ws[WS_YLOG + v];
      float mn = fmaxf(m, lg);
      s = s * __expf(m - mn) + __expf(lg - mn);
      m = mn;
    }
#pragma unroll
    for (int o = 32; o > 0; o >>= 1) {
      float mo = __shfl_xor(m, o, 64), so = __shfl_xor(s, o, 64);
      float mn = fmaxf(m, mo);
      s = s * __expf(m - mn) + so * __expf(mo - mn);
      m = mn;
    }
    if (lane == 0) { rm[w] = m; rv[w] = s; }
  }
  __syncthreads();
  if (t == 0) {
    float M = fmaxf(fmaxf(rm[0], rm[1]), fmaxf(rm[2], rm[3]));
    float S = rv[0]*__expf(rm[0]-M) + rv[1]*__expf(rm[1]-M) +
              rv[2]*__expf(rm[2]-M) + rv[3]*__expf(rm[3]-M);
    ylse_s = M + logf(S);
  }

  for (int i = 0; i < 16; ++i) {
    int l = w * 16 + i, r = b * 64 + l;
    float4 xs = *(const float4*)&ws[WS_XSA0 + (size_t)r * DD + lane * 4];
    float4 k0 = *(const float4*)&xks[lane * 4];
    float4 k1 = *(const float4*)&xks[DD + lane * 4];
    float4 yk4 = *(const float4*)&YK[lane * 4];
    float s0 = waveSum(xs.x*k0.x + xs.y*k0.y + xs.z*k0.z + xs.w*k0.w);
    float s1 = waveSum(xs.x*k1.x + xs.y*k1.y + xs.z*k1.z + xs.w*k1.w);
    float s2 = waveSum(xs.x*yk4.x + xs.y*yk4.y + xs.z*yk4.z + xs.w*yk4.w);
    int xv = x[r];
    float4 e4 = *(const float4*)&embed[(size_t)xv * DD + lane * 4];
    float4 em = *(const float4*)&ws[WS_EMIT + (size_t)r * DD + lane * 4];
    float4 zr = *(const float4*)&ws[WS_ZE + (size_t)r * DD + lane * 4];
    float t0 = waveSum(em.x*e4.x + em.y*e4.y + em.z*e4.z + em.w*e4.w);
    float t1 = waveSum(zr.x*e4.x + zr.y*e4.y + zr.z*e4.z + zr.w*e4.w);
    float m0 = hp[((size_t)r * 64 + lane) * 2];
    float q0 = hp[((size_t)r * 64 + lane) * 2 + 1];
    float m1 = hp[((size_t)(RR + r) * 64 + lane) * 2];
    float q1 = hp[((size_t)(RR + r) * 64 + lane) * 2 + 1];
#pragma unroll
    for (int o = 32; o > 0; o >>= 1) {
      float mo = __shfl_xor(m0, o, 64), so = __shfl_xor(q0, o, 64);
      float mn = fmaxf(m0, mo);
      q0 = q0 * __expf(m0 - mn) + so * __expf(mo - mn);
      m0 = mn;
      mo = __shfl_xor(m1, o, 64); so = __shfl_xor(q1, o, 64);
      mn = fmaxf(m1, mo);
      q1 = q1 * __expf(m1 - mn) + so * __expf(mo - mn);
      m1 = mn;
    }
    if (lane == 0) {
      sel0[l] = s0; sel1[l] = s1; sel2[l] = s2;
      tg0[l] = t0; tg1[l] = t1;
      ls0s[l] = m0 + logf(q0);
      ls1s[l] = m1 + logf(q1);
    }
  }
  __syncthreads();
  if (w == 0) {
    int l = lane, r = b * 64 + l;
    float s0 = sel0[l], s1 = sel1[l], s2 = sel2[l];
    float mx = fmaxf(s0, fmaxf(s1, s2));
    float den = expf(s0 - mx) + expf(s1 - mx) + 64.f * expf(s2 - mx);
    float lsel = mx + logf(den);
    int xv = x[r];
    float P0 = expf(s0 - lsel + tg0[l] - ls0s[l]);
    float P1 = expf(s1 - lsel + tg1[l] - ls1s[l]);
    float Py = expf(s2 - lsel + ws[WS_YLOG + xv] - ylse_s);
    float cent = sqrtf(P0 + P1 + 64.f * Py);
    float sum = waveSum(cent);
    if (lane == 0) out[b] = -(sum * (1.0f / 64.f));
  }
}

extern "C" void kernel_launch(void* const* d_in, const int* in_sizes, int n_in,
                              void* d_out, int out_size, void* d_ws, size_t ws_size,
                              hipStream_t stream) {
  (void)in_sizes; (void)n_in; (void)out_size;
  const int*   x     = (const int*)d_in[0];
  const int*   z     = (const int*)d_in[1];
  const float* embed = (const float*)d_in[2];
  const float* initw = (const float*)d_in[3];
  const float* tw    = (const float*)d_in[4];
  const float* tb    = (const float*)d_in[5];
  const float* cw    = (const float*)d_in[6];
  const float* uw    = (const float*)d_in[7];
  const float* xks   = (const float*)d_in[8];
  const float* xkdw  = (const float*)d_in[9];
  const float* xkdb  = (const float*)d_in[10];
  const float* emiw  = (const float*)d_in[11];
  const float* emib  = (const float*)d_in[12];
  float* ws  = (float*)d_ws;
  float* out = (float*)d_out;

  const bool big = ws_size >= (size_t)WS_BIG_FLOATS * sizeof(float);
  float* hpart = ws + (big ? WS_HPHI : WS_HPART_SMALL);
  const unsigned short* ehg = (const unsigned short*)(ws + WS_EHI);
  const unsigned short* elg = (const unsigned short*)(ws + WS_ELO);

  // P1: ze-norm+zeu3 | yvec/x0vec | transposes | split_e | ylog
  hipLaunchKernelGGL(k_prep1, dim3(RR + 2 + 256 + 1024 + 64), dim3(256), 0,
                     stream, z, embed, initw, tw, cw, uw, tb, ws);
  // P3: z2 + squared-operator matrices + token zero
  hipLaunchKernelGGL(k_prep3, dim3(528), dim3(256), 0, stream, tw, cw, ws);
  // SCAN + emit + (big) head tiles
  hipLaunchKernelGGL(k_scan, dim3(512), dim3(256), 0, stream,
                     ws, emiw, emib, ehg, elg, hpart, big ? 1 : 0);
  // Fallback head (only if hpart must overlay WCT)
  if (!big) {
    hipLaunchKernelGGL(k_head_mfma, dim3(32, 32), dim3(256), 0, stream,
                       ws + WS_EMIT, ws + WS_ZE, ehg, elg, hpart);
  }
  hipLaunchKernelGGL(k_finish, dim3(8), dim3(256), 0, stream,
                     x, embed, xks, xkdw, xkdb, ws, hpart, out);
}

// Round 16
// 349.308 us; speedup vs baseline: 1.0323x; 1.0164x over previous
//
#include <hip/hip_runtime.h>
#include <hip/hip_bf16.h>
#include <math.h>

#define BB 8
#define LL 64
#define DD 256
#define VV 4096
#define RR 512           // BB*LL
#define K3 768

typedef __attribute__((ext_vector_type(4))) float f32x4;
typedef __attribute__((ext_vector_type(8))) short bf16x8;
typedef __attribute__((ext_vector_type(4))) unsigned short u16x4;
typedef unsigned long long u64;

// ---- workspace layout (float offsets) -----------------------------------
#define WS_ZE      0
#define WS_ZEU3    (WS_ZE + RR*DD)           // z; then M5 parts 3,4
#define WS_WCT     (WS_ZEU3 + RR*DD)         // M5 parts 0,1,2
#define WS_XSA0    (WS_WCT + DD*K3)          // scan ping (twT/cwT pre-scan)
#define WS_XSA1    (WS_XSA0 + RR*DD)         // scan pong (z2 at scan start)
#define WS_EMIT    (WS_XSA1 + RR*DD)
#define WS_YVEC    (WS_EMIT + RR*DD)
#define WS_X0VEC   (WS_YVEC + DD)
#define WS_YK      (WS_X0VEC + DD)
#define WS_YLOG    (WS_YK + DD)
#define WS_YLSE    (WS_YLOG + VV)
#define WS_SEL     (WS_YLSE + 8)
// R16 sync: back to R11's best-measured scheme — 64 per-ROWGROUP counter
// lines, 128B (32-int) stride. Each block fetch_adds its rowgroup line per
// step; waiters poll 3 lines (prev/own/next) via lanes 0..2. Line value:
// 8*step during scan, 264 after all 8 siblings' emit.
#define WS_TOKS    WS_SEL
#define WS_HPART_SMALL WS_WCT                // fallback overlay (head post-scan)
// temp (pre-scan only), inside XSA0:
#define WS_TWT     WS_XSA0                   // tw^T
#define WS_CWT     (WS_XSA0 + 65536)         // cw^T
// MFMA tail:
#define WS_EHI     861184
#define WS_ELO     (WS_EHI + VV*DD/2)
#define WS_HPHI    (WS_ELO + VV*DD/2)        // fresh hpart (big mode)
#define WS_BIG_FLOATS (WS_HPHI + 1024*64*2)  // 8,163,328 B (R13/R15-proven)

__device__ __forceinline__ float waveSum(float v) {
#pragma unroll
  for (int o = 32; o > 0; o >>= 1) v += __shfl_xor(v, o, 64);
  return v;
}

__device__ __forceinline__ unsigned short f2bf(float f) {
  unsigned int u = __float_as_uint(f);
  unsigned int r = (u + 0x7fffu + ((u >> 16) & 1u)) >> 16;
  return (unsigned short)r;
}
__device__ __forceinline__ float bf2f(unsigned short h) {
  return __uint_as_float(((unsigned int)h) << 16);
}

union U64F2 { u64 u; float f[2]; };

// --- shared head tile: 32 rows x 128 v, split-bf16 MFMA, online (m,s) ----
// bypass=true: U rows read via agent-scope u64 loads (same-kernel emit).
__device__ __forceinline__ void head_tile(
    int row0, int vy, const float* __restrict__ uemit,
    const float* __restrict__ uze,
    const unsigned short* __restrict__ eh, const unsigned short* __restrict__ el,
    float* __restrict__ hpart, float* shbuf, int t, bool bypass) {
  unsigned short* UH = (unsigned short*)shbuf;
  unsigned short* UL = UH + 32 * 264;
  int lane = t & 63, w = t >> 6;
  int wr = w >> 1, wc = w & 1;
  const float* src = (row0 < RR) ? (uemit + (size_t)row0 * DD)
                                 : (uze + (size_t)(row0 - RR) * DD);
  __syncthreads();   // prior users of shbuf done
#pragma unroll
  for (int it = 0; it < 4; ++it) {
    int r = it * 8 + (t >> 5);
    int c8 = (t & 31) * 8;
    float fa[8];
    if (bypass) {
#pragma unroll
      for (int j = 0; j < 4; ++j) {
        U64F2 v;
        v.u = __hip_atomic_load((const u64*)(src + (size_t)r * DD + c8 + j * 2),
                                __ATOMIC_RELAXED, __HIP_MEMORY_SCOPE_AGENT);
        fa[j * 2] = v.f[0]; fa[j * 2 + 1] = v.f[1];
      }
    } else {
      float4 a = *(const float4*)(src + (size_t)r * DD + c8);
      float4 b2 = *(const float4*)(src + (size_t)r * DD + c8 + 4);
      fa[0]=a.x; fa[1]=a.y; fa[2]=a.z; fa[3]=a.w;
      fa[4]=b2.x; fa[5]=b2.y; fa[6]=b2.z; fa[7]=b2.w;
    }
    u16x4 h0, l0v, h1, l1;
#pragma unroll
    for (int j = 0; j < 4; ++j) {
      unsigned short hb = f2bf(fa[j]);
      h0[j] = hb; l0v[j] = f2bf(fa[j] - bf2f(hb));
      unsigned short hb1 = f2bf(fa[4 + j]);
      h1[j] = hb1; l1[j] = f2bf(fa[4 + j] - bf2f(hb1));
    }
    *(u16x4*)(&UH[r * 264 + c8])     = h0;
    *(u16x4*)(&UH[r * 264 + c8 + 4]) = h1;
    *(u16x4*)(&UL[r * 264 + c8])     = l0v;
    *(u16x4*)(&UL[r * 264 + c8 + 4]) = l1;
  }
  __syncthreads();

  f32x4 acc[4];
#pragma unroll
  for (int q = 0; q < 4; ++q) acc[q] = (f32x4){0.f, 0.f, 0.f, 0.f};

  int arow = wr * 16 + (lane & 15);
  int kof = 8 * (lane >> 4);
  const unsigned short* Ah = &UH[arow * 264 + kof];
  const unsigned short* Al = &UL[arow * 264 + kof];
  int vbase = vy * 128 + wc * 64 + (lane & 15);

#pragma unroll
  for (int p = 0; p < 3; ++p) {
    const unsigned short* Ab = (p == 2) ? Al : Ah;
    const unsigned short* Ebl = ((p == 1) ? el : eh) + (size_t)vbase * DD + kof;
#pragma unroll
    for (int ks = 0; ks < 8; ++ks) {
      int k0 = ks * 32;
      bf16x8 a = *(const bf16x8*)(Ab + k0);
#pragma unroll
      for (int vt = 0; vt < 4; ++vt) {
        bf16x8 bfr = *(const bf16x8*)(Ebl + vt * 16 * DD + k0);
        acc[vt] = __builtin_amdgcn_mfma_f32_16x16x32_bf16(a, bfr, acc[vt], 0, 0, 0);
      }
    }
  }

  int chunk = vy * 2 + wc;
#pragma unroll
  for (int i = 0; i < 4; ++i) {
    float mm = -1e30f;
#pragma unroll
    for (int vt = 0; vt < 4; ++vt) mm = fmaxf(mm, acc[vt][i]);
#pragma unroll
    for (int o = 1; o < 16; o <<= 1) mm = fmaxf(mm, __shfl_xor(mm, o, 64));
    float ss = 0.f;
#pragma unroll
    for (int vt = 0; vt < 4; ++vt) ss += __expf(acc[vt][i] - mm);
#pragma unroll
    for (int o = 1; o < 16; o <<= 1) ss += __shfl_xor(ss, o, 64);
    if ((lane & 15) == 0) {
      int row = row0 + wr * 16 + (lane >> 4) * 4 + i;
      hpart[((size_t)row * 64 + chunk) * 2]     = mm;
      hpart[((size_t)row * 64 + chunk) * 2 + 1] = ss;
    }
  }
}

// --- prep1: ze-norm+zeu3 (0..511) | yvec/x0vec (512,513) | transposes
//            (514..769) | split_e (770..1793) | ylog (1794..1857) ---------
__global__ __launch_bounds__(256) void k_prep1(
    const int* __restrict__ z, const float* __restrict__ embed,
    const float* __restrict__ initw, const float* __restrict__ tw,
    const float* __restrict__ cw, const float* __restrict__ uw,
    const float* __restrict__ tb, float* __restrict__ ws) {
  int bid = blockIdx.x, d = threadIdx.x;
  __shared__ float red[4];
  __shared__ float u[260];
  if (bid < RR + 2) {
    float a; float* dst;
    if (bid < RR) { int tok = z[bid]; a = embed[tok * DD + d]; dst = ws + WS_ZE + bid * DD; }
    else if (bid == RR) { a = embed[d]; dst = ws + WS_YVEC; }
    else { a = initw[d * 16]; dst = ws + WS_X0VEC; }
    int lane = d & 63, w = d >> 6;
    float s = waveSum(a);
    __syncthreads();
    if (lane == 0) red[w] = s;
    __syncthreads();
    float sum = red[0] + red[1] + red[2] + red[3];
    float sq = waveSum(a * a);
    __syncthreads();
    if (lane == 0) red[w] = sq;
    __syncthreads();
    float sqs = red[0] + red[1] + red[2] + red[3];
    float mean = sum * (1.0f / DD);
    float var = fmaxf((sqs - (float)DD * mean * mean) * (1.0f / (DD - 1)), 0.0f);
    float nv = a / (1e-5f + sqrtf(var));
    dst[d] = nv;
    if (bid < RR) {
      // fused zeu3[bid][d] = (ze_row . uw[d,:] + tb[d]) / 3
      u[d] = nv;
      __syncthreads();
      float a0 = 0.f;
      const float4* w4 = (const float4*)(uw + (size_t)d * DD);
      const float4* u0 = (const float4*)&u[0];
#pragma unroll 8
      for (int k4 = 0; k4 < 64; ++k4) {
        float4 wv = w4[k4], x0 = u0[k4];
        a0 += x0.x*wv.x + x0.y*wv.y + x0.z*wv.z + x0.w*wv.w;
      }
      ws[WS_ZEU3 + (size_t)bid * DD + d] = (a0 + tb[d]) * (1.0f / 3.0f);
    }
  } else if (bid < RR + 2 + 256) {
    int c = bid - (RR + 2);
    ws[WS_TWT + c * DD + d] = tw[d * DD + c];
    ws[WS_CWT + c * DD + d] = cw[d * DD + c];
  } else if (bid < RR + 2 + 256 + 1024) {
    int eb = bid - (RR + 2 + 256);
    unsigned short* eh = (unsigned short*)(ws + WS_EHI);
    unsigned short* el = (unsigned short*)(ws + WS_ELO);
    int i = (eb * 256 + d) * 4;
    float4 v = *(const float4*)(embed + i);
    float f[4] = {v.x, v.y, v.z, v.w};
    u16x4 h, l;
#pragma unroll
    for (int j = 0; j < 4; ++j) {
      unsigned short hb = f2bf(f[j]);
      h[j] = hb;
      l[j] = f2bf(f[j] - bf2f(hb));
    }
    *(u16x4*)(eh + i) = h;
    *(u16x4*)(el + i) = l;
  } else {
    // ylog: compute yvec REDUNDANTLY in-block (no cross-block dep)
    int yb = bid - (RR + 2 + 256 + 1024);
    float a = embed[d];
    int lane = d & 63, w = d >> 6;
    float s = waveSum(a);
    __syncthreads();
    if (lane == 0) red[w] = s;
    __syncthreads();
    float sum = red[0] + red[1] + red[2] + red[3];
    float sq = waveSum(a * a);
    __syncthreads();
    if (lane == 0) red[w] = sq;
    __syncthreads();
    float sqs = red[0] + red[1] + red[2] + red[3];
    float mean = sum * (1.0f / DD);
    float var = fmaxf((sqs - (float)DD * mean * mean) * (1.0f / (DD - 1)), 0.0f);
    u[d] = a / (1e-5f + sqrtf(var));
    __syncthreads();
    for (int i = 0; i < 16; i++) {
      int v = yb * 64 + i * 4 + w;
      float p = 0.f;
#pragma unroll
      for (int j = 0; j < 4; j++)
        p += u[lane + 64*j] * embed[(size_t)v * DD + lane + 64*j];
      p = waveSum(p);
      if (lane == 0) ws[WS_YLOG + v] = p;
    }
  }
}

// --- prep3: zmat2 (0..255) + build_w2 (256..511) + zero_tok (512..519) ---
__global__ __launch_bounds__(256) void k_prep3(
    const float* __restrict__ tw, const float* __restrict__ cw,
    float* __restrict__ ws) {
  int bid = blockIdx.x, c = threadIdx.x;
  __shared__ float zs[4][260];
  __shared__ float rA[DD], rB[DD], rC[DD];
  if (bid < 256) {
    // z2[l] = (z[l-1]@A + z[l+1]@B + z[l]@C) + z[l]
    int r0 = bid * 2;
    int b = r0 >> 6, l = r0 & 63;
    const float* zb = ws + WS_ZEU3 + (size_t)b * 64 * DD;
    float* zout = ws + WS_XSA1;
#pragma unroll
    for (int j = 0; j < 4; ++j) {
      int ll = (l + j - 1 + 64) & 63;
      zs[j][c] = zb[ll * DD + c];
    }
    __syncthreads();
    const float4* wA = (const float4*)(ws + WS_TWT + (size_t)c * DD);
    const float4* wB = (const float4*)(tw + (size_t)c * DD);
    const float4* wC = (const float4*)(ws + WS_CWT + (size_t)c * DD);
    const float4* zm0 = (const float4*)&zs[0][0];
    const float4* z00 = (const float4*)&zs[1][0];
    const float4* zp0 = (const float4*)&zs[2][0];
    const float4* zp1 = (const float4*)&zs[3][0];
    float a0 = 0.f, a1 = 0.f;
#pragma unroll 8
    for (int k4 = 0; k4 < 64; ++k4) {
      float4 A4 = wA[k4], B4 = wB[k4], C4 = wC[k4];
      float4 m0 = zm0[k4], z0 = z00[k4], p0 = zp0[k4], p1 = zp1[k4];
      a0 += m0.x*A4.x + m0.y*A4.y + m0.z*A4.z + m0.w*A4.w
          + p0.x*B4.x + p0.y*B4.y + p0.z*B4.z + p0.w*B4.w
          + z0.x*C4.x + z0.y*C4.y + z0.z*C4.z + z0.w*C4.w;
      a1 += z0.x*A4.x + z0.y*A4.y + z0.z*A4.z + z0.w*A4.w
          + p1.x*B4.x + p1.y*B4.y + p1.z*B4.z + p1.w*B4.w
          + p0.x*C4.x + p0.y*C4.y + p0.z*C4.z + p0.w*C4.w;
    }
    const float inv3 = 1.0f / 3.0f;
    zout[(size_t)r0 * DD + c]       = a0 * inv3 + zs[1][c];
    zout[(size_t)(r0 + 1) * DD + c] = a1 * inv3 + zs[2][c];
  } else if (bid < 512) {
    int k = bid - 256;
    const float* twT = ws + WS_TWT;
    const float inv9 = 1.0f / 9.0f;
    rA[c] = tw[k * DD + c] * inv9;
    rB[c] = twT[k * DD + c] * inv9;
    rC[c] = cw[k * DD + c] * inv9;
    __syncthreads();
    float a2 = 0.f, m1 = 0.f, m0 = 0.f, m3 = 0.f, b2 = 0.f;
#pragma unroll 4
    for (int j = 0; j < DD; ++j) {
      float Aj = tw[j * DD + c];
      float Bj = twT[j * DD + c];
      float Cj = cw[j * DD + c];
      float ra = rA[j], rb = rB[j], rc = rC[j];
      a2 += ra * Aj;
      m1 += rc * Aj + ra * Cj;
      m0 += rb * Aj + ra * Bj + rc * Cj;
      m3 += rc * Bj + rb * Cj;
      b2 += rb * Bj;
    }
    float* p0 = ws + WS_WCT;
    float* p3 = ws + WS_ZEU3;
    p0[k * DD + c]               = a2;
    p0[65536 + k * DD + c]       = m1;
    p0[2 * 65536 + k * DD + c]   = m0;
    p3[k * DD + c]               = m3;
    p3[65536 + k * DD + c]       = b2;
  } else {
    ((int*)(ws + WS_TOKS))[(bid - 512) * 256 + c] = 0;
  }
}

// --- persistent scan: 32 squared steps + emit + (big) head tiles ---------
// 512 blocks (2/CU), 256 thr; block = 8 rows x 32 cols; W (K=1280) in 40
// f32x4. R16 sync: R11's best-measured scheme — per-rowgroup counter line,
// fetch_add per block per step, 3-line poll (prev/own/next) via lanes 0..2.
__global__ __launch_bounds__(256, 2) void k_scan(
    float* __restrict__ ws, const float* __restrict__ emiw,
    const float* __restrict__ emib, const unsigned short* __restrict__ eh,
    const unsigned short* __restrict__ el, float* __restrict__ hpart,
    int doHead) {
  const int bid = blockIdx.x;
  const int rg = bid & 63, cg = bid >> 6;
  const int b = rg >> 3, rgl = rg & 7, l0 = rgl * 8;
  const int t = threadIdx.x, lane = t & 63;
  const int cl = t & 7, rs = t >> 3;
  const int c0 = cg * 32 + cl * 4;

  __shared__ float SH[12800];   // scan: S|PAR|PAR2|ZB ; head: UH|UL
  float* S    = SH;             // 12*264 = 3168
  float* PAR  = SH + 3168;      // 32*260 = 8320
  float* PAR2 = SH + 11488;     // 1024
  float* ZB   = SH + 12512;     // 256

  int* tok = (int*)(ws + WS_TOKS);
  const int nb0 = b * 8 + ((rgl + 7) & 7);
  const int nb1 = b * 8 + rgl;
  const int nb2 = b * 8 + ((rgl + 1) & 7);
  const int myl = (lane == 0) ? nb0 : (lane == 1) ? nb1 : nb2;
  const int* pollAddr = tok + myl * 32;
  int* myTok = tok + nb1 * 32;

  const float* Wp[5] = {ws + WS_WCT, ws + WS_WCT + 65536, ws + WS_WCT + 2*65536,
                        ws + WS_ZEU3, ws + WS_ZEU3 + 65536};
  f32x4 wreg[40];
#pragma unroll
  for (int p = 0; p < 5; ++p)
#pragma unroll
    for (int q = 0; q < 2; ++q)
#pragma unroll
      for (int kk = 0; kk < 4; ++kk)
        wreg[p * 8 + q * 4 + kk] =
            *(const f32x4*)&Wp[p][(size_t)(rs * 8 + q * 4 + kk) * DD + c0];

  { // z2 tile from XSA1 (pre-scan by prep3-zmat2)
    int r = t >> 5, c = t & 31;
    ZB[r * 32 + c] = ws[WS_XSA1 + (size_t)(b * 64 + l0 + r) * DD + cg * 32 + c];
  }

  for (int st = 0; st < 32; ++st) {
    const float* xin  = ws + ((st & 1) ? WS_XSA1 : WS_XSA0);
    float*       xout = ws + ((st & 1) ? WS_XSA0 : WS_XSA1);

    if (st > 0) {   // every wave polls: lanes 0..2 cover the 3 counter lines
      const int tg = st << 3;
      while (true) {
        int v = __hip_atomic_load(pollAddr, __ATOMIC_RELAXED,
                                  __HIP_MEMORY_SCOPE_AGENT);
        if (__all(v >= tg)) break;
        __builtin_amdgcn_s_sleep(1);
      }
    }

#pragma unroll
    for (int it = 0; it < 6; ++it) {
      int idx = it * 256 + t;
      int j = idx >> 7;
      int kk = (idx & 127) << 1;
      const u64* src = (st == 0)
          ? (const u64*)(ws + WS_X0VEC + kk)
          : (const u64*)(xin + (size_t)(b * 64 + ((l0 + j - 2 + 64) & 63)) * DD + kk);
      u64 v = __hip_atomic_load(src, __ATOMIC_RELAXED, __HIP_MEMORY_SCOPE_AGENT);
      *(u64*)(&S[j * 264 + kk]) = v;
    }
    __syncthreads();

    f32x4 acc[8];
#pragma unroll
    for (int r = 0; r < 8; ++r) acc[r] = (f32x4){0.f, 0.f, 0.f, 0.f};

#pragma unroll
    for (int p = 0; p < 5; ++p) {
#pragma unroll
      for (int r = 0; r < 8; ++r) {
        int j = r + p;
#pragma unroll
        for (int q = 0; q < 2; ++q) {
          f32x4 xv = *(const f32x4*)&S[j * 264 + rs * 8 + q * 4];
          acc[r] += xv.x * wreg[p * 8 + q * 4 + 0];
          acc[r] += xv.y * wreg[p * 8 + q * 4 + 1];
          acc[r] += xv.z * wreg[p * 8 + q * 4 + 2];
          acc[r] += xv.w * wreg[p * 8 + q * 4 + 3];
        }
      }
    }

#pragma unroll
    for (int r = 0; r < 8; ++r)
      *(f32x4*)&PAR[rs * 260 + r * 32 + cl * 4] = acc[r];
    __syncthreads();

    {
      int u = t & 63, v = t >> 6;
      f32x4 s4 = (f32x4){0.f, 0.f, 0.f, 0.f};
#pragma unroll
      for (int i = 0; i < 8; ++i)
        s4 += *(const f32x4*)&PAR[(v * 8 + i) * 260 + u * 4];
      *(f32x4*)&PAR2[v * 256 + u * 4] = s4;
    }
    __syncthreads();

    if (t < 64) {
      int r = t >> 3, c8 = t & 7;
      f32x4 s4 = (f32x4){0.f, 0.f, 0.f, 0.f};
#pragma unroll
      for (int v = 0; v < 4; ++v)
        s4 += *(const f32x4*)&PAR2[v * 256 + t * 4];
      f32x4 zb = *(const f32x4*)&ZB[r * 32 + c8 * 4];
      s4 += zb;
      size_t off = (size_t)(b * 64 + l0 + r) * DD + cg * 32 + c8 * 4;
      U64F2 lo, hi;
      lo.f[0] = s4.x; lo.f[1] = s4.y;
      hi.f[0] = s4.z; hi.f[1] = s4.w;
      __hip_atomic_store((u64*)(xout + off),     lo.u, __ATOMIC_RELAXED, __HIP_MEMORY_SCOPE_AGENT);
      __hip_atomic_store((u64*)(xout + off + 2), hi.u, __ATOMIC_RELAXED, __HIP_MEMORY_SCOPE_AGENT);
    }

    __syncthreads();   // drains vmcnt(0): bypass stores visible first
    if (t == 0)
      __hip_atomic_fetch_add(myTok, 1, __ATOMIC_RELAXED,
                             __HIP_MEMORY_SCOPE_AGENT);
  }

  // ---- emit tail: wait own rowgroup line == 256, compute, bypass-store ---
  if (t == 0) {
    while (__hip_atomic_load(myTok, __ATOMIC_RELAXED,
                             __HIP_MEMORY_SCOPE_AGENT) < 256)
      __builtin_amdgcn_s_sleep(1);
  }
  __syncthreads();
#pragma unroll
  for (int it = 0; it < 4; ++it) {
    int idx = it * 256 + t;
    int j = idx >> 7;
    int kk = (idx & 127) << 1;
    u64 v = __hip_atomic_load(
        (const u64*)(ws + WS_XSA0 + (size_t)(b * 64 + l0 + j) * DD + kk),
        __ATOMIC_RELAXED, __HIP_MEMORY_SCOPE_AGENT);
    *(u64*)(&S[j * 264 + kk]) = v;
  }
  __syncthreads();
  float* EM = PAR;   // 8 x 32 staging for u64 emit stores
  {
    int r = t >> 5, c = t & 31;
    const float4* wv = (const float4*)(emiw + (size_t)(cg * 32 + c) * DD);
    const float4* xv = (const float4*)&S[r * 264];
    float a = 0.f;
#pragma unroll 8
    for (int k4 = 0; k4 < 64; ++k4) {
      float4 w = wv[k4], x = xv[k4];
      a += x.x*w.x + x.y*w.y + x.z*w.z + x.w*w.w;
    }
    EM[r * 32 + c] = a + emib[cg * 32 + c];
  }
  __syncthreads();
  if (t < 128) {
    int r = t >> 4, c2 = (t & 15) * 2;
    U64F2 v;
    v.f[0] = EM[r * 32 + c2];
    v.f[1] = EM[r * 32 + c2 + 1];
    __hip_atomic_store(
        (u64*)(ws + WS_EMIT + (size_t)(b * 64 + l0 + r) * DD + cg * 32 + c2),
        v.u, __ATOMIC_RELAXED, __HIP_MEMORY_SCOPE_AGENT);
  }
  __syncthreads();   // drain emit stores before the post-emit add
  if (t == 0)
    __hip_atomic_fetch_add(myTok, 1, __ATOMIC_RELAXED, __HIP_MEMORY_SCOPE_AGENT);
  // line reaches 264 when all 8 siblings have emitted

  if (!doHead) return;

  // ---- head phase (sequential, 2 tiles per block) -------------------------
  // T1: ZE tile (rows 512+, inputs ready pre-launch) — no wait.
  {
    int T1 = bid + 512;
    head_tile((T1 >> 5) * 32, T1 & 31, ws + WS_EMIT, ws + WS_ZE,
              eh, el, hpart, SH, t, false);
  }
  // T0: EMIT tile — wait for the 4 covered rowgroups' lines to reach 264.
  {
    int ri0 = bid >> 5, vc0 = bid & 31;
    const int* ta = tok + (ri0 * 4 + (lane & 3)) * 32;
    while (true) {
      int v = __hip_atomic_load(ta, __ATOMIC_RELAXED, __HIP_MEMORY_SCOPE_AGENT);
      if (__all(v >= 264)) break;
      __builtin_amdgcn_s_sleep(1);
    }
    head_tile(ri0 * 32, vc0, ws + WS_EMIT, ws + WS_ZE,
              eh, el, hpart, SH, t, true);
  }
}

// --- standalone head kernel (fallback, !big) ------------------------------
__global__ __launch_bounds__(256) void k_head_mfma(
    const float* __restrict__ uemit, const float* __restrict__ uze,
    const unsigned short* __restrict__ eh, const unsigned short* __restrict__ el,
    float* __restrict__ hpart) {
  __shared__ float SH[8448];
  head_tile(blockIdx.x * 32, blockIdx.y, uemit, uze, eh, el, hpart, SH,
            threadIdx.x, false);
}

// --- finish: yk + ylse + sel + tgt + comb + final, fused; grid(8) --------
__global__ __launch_bounds__(256) void k_finish(
    const int* __restrict__ x, const float* __restrict__ embed,
    const float* __restrict__ xks, const float* __restrict__ xkdw,
    const float* __restrict__ xkdb, float* __restrict__ ws,
    const float* __restrict__ hp, float* __restrict__ out) {
  int b = blockIdx.x, t = threadIdx.x, lane = t & 63, w = t >> 6;
  __shared__ float YK[DD];
  __shared__ float rm[4], rv[4];
  __shared__ float ylse_s;
  __shared__ float sel0[64], sel1[64], sel2[64], tg0[64], tg1[64];
  __shared__ float ls0s[64], ls1s[64];

  {
    float acc = xkdb[t];
    const float4* yv4 = (const float4*)(ws + WS_YVEC);
    const float4* w4 = (const float4*)(xkdw + (size_t)t * DD);
    float a = 0.f;
#pragma unroll 8
    for (int k4 = 0; k4 < 64; ++k4) {
      float4 yv = yv4[k4], wv = w4[k4];
      a += yv.x*wv.x + yv.y*wv.y + yv.z*wv.z + yv.w*wv.w;
    }
    YK[t] = acc + a;
  }
  {
    float m = -1e30f, s = 0.f;
    for (int v = t; v < VV; v += 256) {
      float lg = ws[WS_YLOG + v];
      float mn = fmaxf(m, lg);
      s = s * __expf(m - mn) + __expf(lg - mn);
      m = mn;
    }
#pragma unroll
    for (int o = 32; o > 0; o >>= 1) {
      float mo = __shfl_xor(m, o, 64), so = __shfl_xor(s, o, 64);
      float mn = fmaxf(m, mo);
      s = s * __expf(m - mn) + so * __expf(mo - mn);
      m = mn;
    }
    if (lane == 0) { rm[w] = m; rv[w] = s; }
  }
  __syncthreads();
  if (t == 0) {
    float M = fmaxf(fmaxf(rm[0], rm[1]), fmaxf(rm[2], rm[3]));
    float S = rv[0]*__expf(rm[0]-M) + rv[1]*__expf(rm[1]-M) +
              rv[2]*__expf(rm[2]-M) + rv[3]*__expf(rm[3]-M);
    ylse_s = M + logf(S);
  }

  for (int i = 0; i < 16; ++i) {
    int l = w * 16 + i, r = b * 64 + l;
    float4 xs = *(const float4*)&ws[WS_XSA0 + (size_t)r * DD + lane * 4];
    float4 k0 = *(const float4*)&xks[lane * 4];
    float4 k1 = *(const float4*)&xks[DD + lane * 4];
    float4 yk4 = *(const float4*)&YK[lane * 4];
    float s0 = waveSum(xs.x*k0.x + xs.y*k0.y + xs.z*k0.z + xs.w*k0.w);
    float s1 = waveSum(xs.x*k1.x + xs.y*k1.y + xs.z*k1.z + xs.w*k1.w);
    float s2 = waveSum(xs.x*yk4.x + xs.y*yk4.y + xs.z*yk4.z + xs.w*yk4.w);
    int xv = x[r];
    float4 e4 = *(const float4*)&embed[(size_t)xv * DD + lane * 4];
    float4 em = *(const float4*)&ws[WS_EMIT + (size_t)r * DD + lane * 4];
    float4 zr = *(const float4*)&ws[WS_ZE + (size_t)r * DD + lane * 4];
    float t0 = waveSum(em.x*e4.x + em.y*e4.y + em.z*e4.z + em.w*e4.w);
    float t1 = waveSum(zr.x*e4.x + zr.y*e4.y + zr.z*e4.z + zr.w*e4.w);
    float m0 = hp[((size_t)r * 64 + lane) * 2];
    float q0 = hp[((size_t)r * 64 + lane) * 2 + 1];
    float m1 = hp[((size_t)(RR + r) * 64 + lane) * 2];
    float q1 = hp[((size_t)(RR + r) * 64 + lane) * 2 + 1];
#pragma unroll
    for (int o = 32; o > 0; o >>= 1) {
      float mo = __shfl_xor(m0, o, 64), so = __shfl_xor(q0, o, 64);
      float mn = fmaxf(m0, mo);
      q0 = q0 * __expf(m0 - mn) + so * __expf(mo - mn);
      m0 = mn;
      mo = __shfl_xor(m1, o, 64); so = __shfl_xor(q1, o, 64);
      mn = fmaxf(m1, mo);
      q1 = q1 * __expf(m1 - mn) + so * __expf(mo - mn);
      m1 = mn;
    }
    if (lane == 0) {
      sel0[l] = s0; sel1[l] = s1; sel2[l] = s2;
      tg0[l] = t0; tg1[l] = t1;
      ls0s[l] = m0 + logf(q0);
      ls1s[l] = m1 + logf(q1);
    }
  }
  __syncthreads();
  if (w == 0) {
    int l = lane, r = b * 64 + l;
    float s0 = sel0[l], s1 = sel1[l], s2 = sel2[l];
    float mx = fmaxf(s0, fmaxf(s1, s2));
    float den = expf(s0 - mx) + expf(s1 - mx) + 64.f * expf(s2 - mx);
    float lsel = mx + logf(den);
    int xv = x[r];
    float P0 = expf(s0 - lsel + tg0[l] - ls0s[l]);
    float P1 = expf(s1 - lsel + tg1[l] - ls1s[l]);
    float Py = expf(s2 - lsel + ws[WS_YLOG + xv] - ylse_s);
    float cent = sqrtf(P0 + P1 + 64.f * Py);
    float sum = waveSum(cent);
    if (lane == 0) out[b] = -(sum * (1.0f / 64.f));
  }
}

extern "C" void kernel_launch(void* const* d_in, const int* in_sizes, int n_in,
                              void* d_out, int out_size, void* d_ws, size_t ws_size,
                              hipStream_t stream) {
  (void)in_sizes; (void)n_in; (void)out_size;
  const int*   x     = (const int*)d_in[0];
  const int*   z     = (const int*)d_in[1];
  const float* embed = (const float*)d_in[2];
  const float* initw = (const float*)d_in[3];
  const float* tw    = (const float*)d_in[4];
  const float* tb    = (const float*)d_in[5];
  const float* cw    = (const float*)d_in[6];
  const float* uw    = (const float*)d_in[7];
  const float* xks   = (const float*)d_in[8];
  const float* xkdw  = (const float*)d_in[9];
  const float* xkdb  = (const float*)d_in[10];
  const float* emiw  = (const float*)d_in[11];
  const float* emib  = (const float*)d_in[12];
  float* ws  = (float*)d_ws;
  float* out = (float*)d_out;

  const bool big = ws_size >= (size_t)WS_BIG_FLOATS * sizeof(float);
  float* hpart = ws + (big ? WS_HPHI : WS_HPART_SMALL);
  const unsigned short* ehg = (const unsigned short*)(ws + WS_EHI);
  const unsigned short* elg = (const unsigned short*)(ws + WS_ELO);

  // P1: ze-norm+zeu3 | yvec/x0vec | transposes | split_e | ylog
  hipLaunchKernelGGL(k_prep1, dim3(RR + 2 + 256 + 1024 + 64), dim3(256), 0,
                     stream, z, embed, initw, tw, cw, uw, tb, ws);
  // P3: z2 + squared-operator matrices + token zero
  hipLaunchKernelGGL(k_prep3, dim3(520), dim3(256), 0, stream, tw, cw, ws);
  // SCAN + emit + (big) head tiles
  hipLaunchKernelGGL(k_scan, dim3(512), dim3(256), 0, stream,
                     ws, emiw, emib, ehg, elg, hpart, big ? 1 : 0);
  // Fallback head (only if hpart must overlay WCT)
  if (!big) {
    hipLaunchKernelGGL(k_head_mfma, dim3(32, 32), dim3(256), 0, stream,
                       ws + WS_EMIT, ws + WS_ZE, ehg, elg, hpart);
  }
  hipLaunchKernelGGL(k_finish, dim3(8), dim3(256), 0, stream,
                     x, embed, xks, xkdw, xkdb, ws, hpart, out);
}